// Round 1
// baseline (910.910 us; speedup 1.0000x reference)
//
#include <hip/hip_runtime.h>

#define Mm   8
#define Ee   144
#define IO   256            // idim*odim = 16*16
#define S1   5
#define NM   64             // n = s*mode
#define MH   33             // n/2+1
#define ABTOT 20736         // 144*144
#define GSZ  (S1*Mm*Mm*IO)  // 81920 floats per direction
#define NPOS 4

__device__ __forceinline__ float getc(const float4& v, int c) {
    return c == 0 ? v.x : c == 1 ? v.y : c == 2 ? v.z : v.w;
}

// ---------------------------------------------------------------------------
// Kernel A: build G[d][k][X][x][i][o] = ws_d[k,X,x] * fourier(coef_d, xy)[X,x,i,o]
// grid: 640 blocks (2 dirs * 5 k * 64 (X,x)), 256 threads (one per (i,o))
// ---------------------------------------------------------------------------
__global__ void build_g_kernel(const float* __restrict__ coef0,
                               const float* __restrict__ coef1,
                               const float* __restrict__ ws0,
                               const float* __restrict__ ws1,
                               const float* __restrict__ grid,
                               float* __restrict__ G)
{
    const int bid = blockIdx.x;                 // 0..639
    const int d   = (bid >= 320) ? 1 : 0;
    const int rem = bid - d * 320;
    const int k   = rem >> 6;
    const int X   = (rem >> 3) & 7;
    const int x   = rem & 7;

    const float* __restrict__ coef = d ? coef1 : coef0;
    const float* __restrict__ ws   = d ? ws1 : ws0;
    float* __restrict__ g = G + d * GSZ;

    const float xy = (grid[X] - (grid[x] + (float)(k - 2))) * 0.25f;
    const int t = threadIdx.x;                  // t = i*16 + o

    float acc = 0.f;
    #pragma unroll 1
    for (int j = 0; j < MH; ++j) {
        float ang = 6.283185307179586f * (float)j * xy;
        float c = cosf(ang);
        float s = sinf(ang);
        float sc = (j == 0 || j == MH - 1) ? 1.f : 2.f;
        float rr = coef[j * IO + t];
        float ii = (j >= 1 && j <= MH - 2) ? coef[(NM - j) * IO + t] : 0.f;
        acc += sc * (c * rr - s * ii);
    }
    g[((k * Mm + X) * Mm + x) * IO + t] = acc * ws[(k * Mm + X) * Mm + x];
}

// ---------------------------------------------------------------------------
// Kernel B: out[p,q,a,b,o] = sum_k,x,i nodal[x,q,am,b,i]*G0[k,p,x,i,o]
//                          + sum_k,y,i nodal[p,y,a,bm,i]*G1[k,q,y,i,o]
// grid: (21 tiles of 1024 (a,b) positions, 64 (p,q)), 256 threads
// each thread: 4 positions x 16 outputs
// ---------------------------------------------------------------------------
__global__ __launch_bounds__(256, 2)
void sem_conv_kernel(const float* __restrict__ nodal,
                     const float* __restrict__ G,
                     float* __restrict__ out)
{
    __shared__ __align__(16) float w0[S1 * Mm * IO];   // 10240 floats = 40KB
    __shared__ __align__(16) float w1[S1 * Mm * IO];   // 40KB

    const int t  = threadIdx.x;
    const int pq = blockIdx.y;
    const int p  = pq >> 3;
    const int q  = pq & 7;

    // ---- stage per-(p,q) weight slices into LDS ----
    {
        const float4* __restrict__ G4 = (const float4*)G;
        float4* w04 = (float4*)w0;
        float4* w14 = (float4*)w1;
        #pragma unroll
        for (int it = 0; it < 10; ++it) {
            int j4   = it * 256 + t;         // 0..2559
            int kk   = j4 >> 9;              // /512 (one (k,X) slice = 2048 floats)
            int rest = j4 & 511;
            w04[j4] = G4[(kk * Mm + p) * 512 + rest];
            w14[j4] = G4[(GSZ / 4) + (kk * Mm + q) * 512 + rest];
        }
    }
    __syncthreads();

    // ---- positions ----
    int aa[NPOS], bb[NPOS], abi[NPOS];
    bool valid[NPOS];
    const int abase = blockIdx.x * (256 * NPOS);
    #pragma unroll
    for (int pp = 0; pp < NPOS; ++pp) {
        int ab = abase + pp * 256 + t;
        valid[pp] = (ab < ABTOT);
        if (!valid[pp]) ab = 0;
        abi[pp] = ab;
        aa[pp] = ab / Ee;
        bb[pp] = ab - aa[pp] * Ee;
    }

    float acc[NPOS][16];
    #pragma unroll
    for (int pp = 0; pp < NPOS; ++pp)
        #pragma unroll
        for (int o = 0; o < 16; ++o) acc[pp][o] = 0.f;

    // ---- term 0: conv along a, contract (x, i), weights w0[k][x][i][o] ----
    #pragma unroll 1
    for (int k = 0; k < S1; ++k) {
        int off0[NPOS];
        #pragma unroll
        for (int pp = 0; pp < NPOS; ++pp) {
            int am = aa[pp] + (k - 2);
            am += (am < 0) ? Ee : 0;
            am -= (am >= Ee) ? Ee : 0;
            off0[pp] = (q * Ee + am) * Ee + bb[pp];   // add x*165888 inside loop
        }
        #pragma unroll 1
        for (int x = 0; x < Mm; ++x) {
            float4 n4[NPOS][4];
            #pragma unroll
            for (int pp = 0; pp < NPOS; ++pp) {
                const float4* src =
                    (const float4*)(nodal + (size_t)(x * 165888 + off0[pp]) * 16);
                n4[pp][0] = src[0];
                n4[pp][1] = src[1];
                n4[pp][2] = src[2];
                n4[pp][3] = src[3];
            }
            const float* wb = w0 + (k * Mm + x) * IO;
            #pragma unroll
            for (int i = 0; i < 16; ++i) {
                float4 wv[4];
                #pragma unroll
                for (int u = 0; u < 4; ++u)
                    wv[u] = *(const float4*)(wb + i * 16 + u * 4);
                #pragma unroll
                for (int pp = 0; pp < NPOS; ++pp) {
                    float nv = getc(n4[pp][i >> 2], i & 3);
                    #pragma unroll
                    for (int o = 0; o < 16; ++o)
                        acc[pp][o] = fmaf(nv, getc(wv[o >> 2], o & 3), acc[pp][o]);
                }
            }
        }
    }

    // ---- term 1: conv along b, contract (y, i), weights w1[k][y][i][o] ----
    #pragma unroll 1
    for (int k = 0; k < S1; ++k) {
        int off1[NPOS];
        #pragma unroll
        for (int pp = 0; pp < NPOS; ++pp) {
            int bm = bb[pp] + (k - 2);
            bm += (bm < 0) ? Ee : 0;
            bm -= (bm >= Ee) ? Ee : 0;
            off1[pp] = p * 165888 + aa[pp] * Ee + bm;  // add y*20736 inside loop
        }
        #pragma unroll 1
        for (int y = 0; y < Mm; ++y) {
            float4 n4[NPOS][4];
            #pragma unroll
            for (int pp = 0; pp < NPOS; ++pp) {
                const float4* src =
                    (const float4*)(nodal + (size_t)(off1[pp] + y * 20736) * 16);
                n4[pp][0] = src[0];
                n4[pp][1] = src[1];
                n4[pp][2] = src[2];
                n4[pp][3] = src[3];
            }
            const float* wb = w1 + (k * Mm + y) * IO;
            #pragma unroll
            for (int i = 0; i < 16; ++i) {
                float4 wv[4];
                #pragma unroll
                for (int u = 0; u < 4; ++u)
                    wv[u] = *(const float4*)(wb + i * 16 + u * 4);
                #pragma unroll
                for (int pp = 0; pp < NPOS; ++pp) {
                    float nv = getc(n4[pp][i >> 2], i & 3);
                    #pragma unroll
                    for (int o = 0; o < 16; ++o)
                        acc[pp][o] = fmaf(nv, getc(wv[o >> 2], o & 3), acc[pp][o]);
                }
            }
        }
    }

    // ---- store ----
    float* ob = out + (size_t)pq * (ABTOT * 16);
    #pragma unroll
    for (int pp = 0; pp < NPOS; ++pp) {
        if (valid[pp]) {
            float4* dst = (float4*)(ob + (size_t)abi[pp] * 16);
            dst[0] = make_float4(acc[pp][0], acc[pp][1], acc[pp][2], acc[pp][3]);
            dst[1] = make_float4(acc[pp][4], acc[pp][5], acc[pp][6], acc[pp][7]);
            dst[2] = make_float4(acc[pp][8], acc[pp][9], acc[pp][10], acc[pp][11]);
            dst[3] = make_float4(acc[pp][12], acc[pp][13], acc[pp][14], acc[pp][15]);
        }
    }
}

extern "C" void kernel_launch(void* const* d_in, const int* in_sizes, int n_in,
                              void* d_out, int out_size, void* d_ws, size_t ws_size,
                              hipStream_t stream) {
    const float* nodal = (const float*)d_in[0];
    const float* coef0 = (const float*)d_in[1];
    const float* coef1 = (const float*)d_in[2];
    const float* ws0   = (const float*)d_in[3];
    const float* ws1   = (const float*)d_in[4];
    const float* grid  = (const float*)d_in[5];
    float* outp = (float*)d_out;
    float* G    = (float*)d_ws;            // 2 * 81920 floats = 640KB scratch

    hipLaunchKernelGGL(build_g_kernel, dim3(640), dim3(256), 0, stream,
                       coef0, coef1, ws0, ws1, grid, G);

    dim3 grd(21, 64);   // 21 tiles of 1024 positions, 64 (p,q)
    hipLaunchKernelGGL(sem_conv_kernel, grd, dim3(256), 0, stream,
                       nodal, G, outp);
}

// Round 2
// 254.823 us; speedup vs baseline: 3.5747x; 3.5747x over previous
//
#include <hip/hip_runtime.h>

typedef __attribute__((ext_vector_type(8))) short short8;
typedef __attribute__((ext_vector_type(4))) float f32x4;

#define NODAL_ELEMS 21233664     // 8*8*144*144*16
#define BSLAB 81920              // 640*128 elements per direction
#define NB_OFF 327680            // byte offset of bf16 nodal in ws (2*BSLAB*2)

__device__ __forceinline__ unsigned short f2bf(float f) {
    unsigned int u = __float_as_uint(f);
    u += 0x7FFFu + ((u >> 16) & 1u);     // RNE
    return (unsigned short)(u >> 16);
}

// ---------------------------------------------------------------------------
// Build B matrices in fragment-order layout: B[d][kk=K/8][n=0..127][j=K%8]
// K = k*128 + x*16 + i ; n = X*16 + o ; value = ws[k,X,x]*fourier(coef,xy)[i,o]
// grid: 640 blocks (2 dir * 5 k * 8 X * 8 x), 256 threads (t = i*16+o)
// ---------------------------------------------------------------------------
__global__ void build_b_kernel(const float* __restrict__ coef0,
                               const float* __restrict__ coef1,
                               const float* __restrict__ ws0,
                               const float* __restrict__ ws1,
                               const float* __restrict__ grid,
                               unsigned short* __restrict__ B)
{
    const int bid = blockIdx.x;
    const int d   = (bid >= 320) ? 1 : 0;
    const int rem = bid - d * 320;
    const int k   = rem >> 6;
    const int X   = (rem >> 3) & 7;
    const int x   = rem & 7;

    const float* __restrict__ coef = d ? coef1 : coef0;
    const float* __restrict__ ws   = d ? ws1 : ws0;
    unsigned short* __restrict__ Bd = B + d * BSLAB;

    const float xy = (grid[X] - (grid[x] + (float)(k - 2))) * 0.25f;
    const int t = threadIdx.x;          // i*16 + o
    const int i = t >> 4;
    const int o = t & 15;

    float acc = 0.f;
    #pragma unroll 1
    for (int j = 0; j < 33; ++j) {
        float ang = 6.283185307179586f * (float)j * xy;
        float c = cosf(ang);
        float s = sinf(ang);
        float sc = (j == 0 || j == 32) ? 1.f : 2.f;
        float rr = coef[j * 256 + t];
        float ii = (j >= 1 && j <= 31) ? coef[(64 - j) * 256 + t] : 0.f;
        acc += sc * (c * rr - s * ii);
    }
    float val = acc * ws[(k * 8 + X) * 8 + x];

    const int kk = k * 16 + x * 2 + (i >> 3);
    const int jj = i & 7;
    const int n  = X * 16 + o;
    Bd[(kk * 128 + n) * 8 + jj] = f2bf(val);
}

// ---------------------------------------------------------------------------
// nodal fp32 -> bf16
// ---------------------------------------------------------------------------
__global__ void cvt_kernel(const float* __restrict__ in,
                           unsigned short* __restrict__ out, int n4)
{
    int idx = blockIdx.x * blockDim.x + threadIdx.x;
    int stride = gridDim.x * blockDim.x;
    for (int j = idx; j < n4; j += stride) {
        float4 v = ((const float4*)in)[j];
        ushort4 r;
        r.x = f2bf(v.x); r.y = f2bf(v.y); r.z = f2bf(v.z); r.w = f2bf(v.w);
        ((ushort4*)out)[j] = r;
    }
}

// ---------------------------------------------------------------------------
// MFMA conv kernel. TERM=0: fixed q, contract (k,x,i), N=(p,o), writes out.
//                  TERM=1: fixed p, contract (k,y,i), N=(q,o), accumulates.
// Block: 256 thr (4 waves). Tile: M=256 (wave owns 64 rows), N=128, K=640.
// grid: (81 M-tiles, 8 XF)
// ---------------------------------------------------------------------------
template<int TERM, bool AB16>
__global__ __launch_bounds__(256, 2)
void conv_mfma(const float* __restrict__ nodalf,
               const unsigned short* __restrict__ nodalb,
               const unsigned short* __restrict__ Bmat,
               float* __restrict__ out)
{
    const int tid = threadIdx.x;
    const int w   = tid >> 6;
    const int l   = tid & 63;
    const int sub = l >> 4;
    const int lr  = l & 15;
    const int mtile = blockIdx.x;       // 0..80
    const int XF    = blockIdx.y;       // q (TERM0) / p (TERM1)

    // scalar pointer fold: TERM0 += q*331776 ; TERM1 += p*2654208 (elems)
    const int scal = (TERM == 0) ? XF * 331776 : XF * 2654208;
    const int KSTR = (TERM == 0) ? 2654208 : 331776;   // x / y stride (elems)

    // per-lane per-mf base element offsets (includes lane K-sub placement)
    int base[4][5];
    const int rowbase = mtile * 256 + w * 64;
    #pragma unroll
    for (int mf = 0; mf < 4; ++mf) {
        int row = rowbase + mf * 16 + lr;
        int a = row / 144;
        int b = row - a * 144;
        #pragma unroll
        for (int k = 0; k < 5; ++k) {
            int sh = ((TERM == 0) ? a : b) + k - 2;
            if (sh < 0) sh += 144;
            if (sh >= 144) sh -= 144;
            int off = (TERM == 0) ? (sh * 2304 + b * 16) : (a * 2304 + sh * 16);
            base[mf][k] = off + (sub >> 1) * KSTR + (sub & 1) * 8;
        }
    }

    const int bvoff = sub * 2048 + lr * 16;   // bytes; + ks*8192 + nf*256

    f32x4 acc[4][8];
    #pragma unroll
    for (int mf = 0; mf < 4; ++mf)
        #pragma unroll
        for (int nf = 0; nf < 8; ++nf)
            acc[mf][nf] = (f32x4){0.f, 0.f, 0.f, 0.f};

    const unsigned short* nb = nodalb + scal;
    const float* nfp = nodalf + scal;
    const char* Bb = (const char*)Bmat;

    #pragma unroll
    for (int ks = 0; ks < 20; ++ks) {
        const int k  = ks >> 2;                 // compile-time (full unroll)
        const int xs = (ks & 3) * 2 * KSTR;     // scalar element offset

        short8 af[4];
        if (AB16) {
            #pragma unroll
            for (int mf = 0; mf < 4; ++mf)
                af[mf] = *(const short8*)(nb + base[mf][k] + xs);
        } else {
            #pragma unroll
            for (int mf = 0; mf < 4; ++mf) {
                const float* s = nfp + base[mf][k] + xs;
                float4 v0 = *(const float4*)s;
                float4 v1 = *(const float4*)(s + 4);
                short8 t;
                t[0] = (short)f2bf(v0.x); t[1] = (short)f2bf(v0.y);
                t[2] = (short)f2bf(v0.z); t[3] = (short)f2bf(v0.w);
                t[4] = (short)f2bf(v1.x); t[5] = (short)f2bf(v1.y);
                t[6] = (short)f2bf(v1.z); t[7] = (short)f2bf(v1.w);
                af[mf] = t;
            }
        }

        #pragma unroll
        for (int nf = 0; nf < 8; ++nf) {
            short8 bf = *(const short8*)(Bb + bvoff + ks * 8192 + nf * 256);
            #pragma unroll
            for (int mf = 0; mf < 4; ++mf)
                acc[mf][nf] = __builtin_amdgcn_mfma_f32_16x16x32_bf16(
                    af[mf], bf, acc[mf][nf], 0, 0, 0);
        }
    }

    // ---- store: C frag layout col=lane&15, row=(lane>>4)*4+reg ----
    // n = nf*16 + lr  ->  P-index = nf, o = lr
    const int orow0 = mtile * 256 + w * 64 + sub * 4;
    #pragma unroll
    for (int mf = 0; mf < 4; ++mf) {
        #pragma unroll
        for (int nf = 0; nf < 8; ++nf) {
            int pq = (TERM == 0) ? (nf * 2654208 + XF * 331776)
                                 : (XF * 2654208 + nf * 331776);
            int b0 = pq + (orow0 + mf * 16) * 16 + lr;
            #pragma unroll
            for (int r = 0; r < 4; ++r) {
                float v = acc[mf][nf][r];
                if (TERM == 0) out[b0 + r * 16] = v;
                else           out[b0 + r * 16] += v;
            }
        }
    }
}

extern "C" void kernel_launch(void* const* d_in, const int* in_sizes, int n_in,
                              void* d_out, int out_size, void* d_ws, size_t ws_size,
                              hipStream_t stream) {
    const float* nodal = (const float*)d_in[0];
    const float* coef0 = (const float*)d_in[1];
    const float* coef1 = (const float*)d_in[2];
    const float* ws0   = (const float*)d_in[3];
    const float* ws1   = (const float*)d_in[4];
    const float* grid  = (const float*)d_in[5];
    float* outp = (float*)d_out;

    unsigned short* B      = (unsigned short*)d_ws;
    unsigned short* nodalb = (unsigned short*)((char*)d_ws + NB_OFF);
    const bool ab16 = ws_size >= (size_t)NB_OFF + (size_t)NODAL_ELEMS * 2;

    hipLaunchKernelGGL(build_b_kernel, dim3(640), dim3(256), 0, stream,
                       coef0, coef1, ws0, ws1, grid, B);
    if (ab16)
        hipLaunchKernelGGL(cvt_kernel, dim3(2048), dim3(256), 0, stream,
                           nodal, nodalb, NODAL_ELEMS / 4);

    dim3 g(81, 8);
    if (ab16) {
        hipLaunchKernelGGL((conv_mfma<0, true>), g, dim3(256), 0, stream,
                           nodal, nodalb, B, outp);
        hipLaunchKernelGGL((conv_mfma<1, true>), g, dim3(256), 0, stream,
                           nodal, nodalb, B + BSLAB, outp);
    } else {
        hipLaunchKernelGGL((conv_mfma<0, false>), g, dim3(256), 0, stream,
                           nodal, nodalb, B, outp);
        hipLaunchKernelGGL((conv_mfma<1, false>), g, dim3(256), 0, stream,
                           nodal, nodalb, B + BSLAB, outp);
    }
}

// Round 3
// 148.520 us; speedup vs baseline: 6.1333x; 1.7158x over previous
//
#include <hip/hip_runtime.h>

typedef __attribute__((ext_vector_type(8))) short short8;
typedef __attribute__((ext_vector_type(4))) float f32x4;

#define NODAL_ELEMS 21233664     // 8*8*144*144*16
#define BSLAB 81920              // 640*128 elements per direction
#define NB_OFF 327680            // byte offset of bf16 nodal in ws (2*BSLAB*2)

__device__ __forceinline__ unsigned short f2bf(float f) {
    unsigned int u = __float_as_uint(f);
    u += 0x7FFFu + ((u >> 16) & 1u);     // RNE
    return (unsigned short)(u >> 16);
}

__device__ __forceinline__ void gload_lds16(const void* g, void* l) {
    __builtin_amdgcn_global_load_lds(
        (const __attribute__((address_space(1))) unsigned int*)g,
        (__attribute__((address_space(3))) unsigned int*)l, 16, 0, 0);
}

// ---------------------------------------------------------------------------
// Build B matrices in fragment-order layout: B[d][kk=K/8][n=0..127][j=K%8]
// K = k*128 + x*16 + i ; n = X*16 + o ; value = ws[k,X,x]*fourier(coef,xy)[i,o]
// ---------------------------------------------------------------------------
__global__ void build_b_kernel(const float* __restrict__ coef0,
                               const float* __restrict__ coef1,
                               const float* __restrict__ ws0,
                               const float* __restrict__ ws1,
                               const float* __restrict__ grid,
                               unsigned short* __restrict__ B)
{
    const int bid = blockIdx.x;
    const int d   = (bid >= 320) ? 1 : 0;
    const int rem = bid - d * 320;
    const int k   = rem >> 6;
    const int X   = (rem >> 3) & 7;
    const int x   = rem & 7;

    const float* __restrict__ coef = d ? coef1 : coef0;
    const float* __restrict__ ws   = d ? ws1 : ws0;
    unsigned short* __restrict__ Bd = B + d * BSLAB;

    const float xy = (grid[X] - (grid[x] + (float)(k - 2))) * 0.25f;
    const int t = threadIdx.x;          // i*16 + o
    const int i = t >> 4;
    const int o = t & 15;

    float acc = 0.f;
    #pragma unroll 1
    for (int j = 0; j < 33; ++j) {
        float ang = 6.283185307179586f * (float)j * xy;
        float c = cosf(ang);
        float s = sinf(ang);
        float sc = (j == 0 || j == 32) ? 1.f : 2.f;
        float rr = coef[j * 256 + t];
        float ii = (j >= 1 && j <= 31) ? coef[(64 - j) * 256 + t] : 0.f;
        acc += sc * (c * rr - s * ii);
    }
    float val = acc * ws[(k * 8 + X) * 8 + x];

    const int kk = k * 16 + x * 2 + (i >> 3);
    const int jj = i & 7;
    const int n  = X * 16 + o;
    Bd[(kk * 128 + n) * 8 + jj] = f2bf(val);
}

// ---------------------------------------------------------------------------
// nodal fp32 -> bf16
// ---------------------------------------------------------------------------
__global__ void cvt_kernel(const float* __restrict__ in,
                           unsigned short* __restrict__ out, int n4)
{
    int idx = blockIdx.x * blockDim.x + threadIdx.x;
    int stride = gridDim.x * blockDim.x;
    for (int j = idx; j < n4; j += stride) {
        float4 v = ((const float4*)in)[j];
        ushort4 r;
        r.x = f2bf(v.x); r.y = f2bf(v.y); r.z = f2bf(v.z); r.w = f2bf(v.w);
        ((ushort4*)out)[j] = r;
    }
}

// ---------------------------------------------------------------------------
// MFMA conv kernel. TERM=0: fixed q, contract (k,x,i), N=(p,o), writes out.
//                  TERM=1: fixed p, contract (k,y,i), N=(q,o), accumulates.
// Block: 256 thr (4 waves). Tile: M=128 (wave M32xN128), N=128, K=640.
// B staged in LDS (8KB/K-step, double-buffered, global_load_lds DMA).
// A per-lane global->reg, prefetch depth 2.
// grid: (162 M-tiles, 8 XF)
// ---------------------------------------------------------------------------
template<int TERM, bool AB16>
__global__ __launch_bounds__(256, 3)
void conv_mfma(const float* __restrict__ nodalf,
               const unsigned short* __restrict__ nodalb,
               const unsigned short* __restrict__ Bmat,
               float* __restrict__ out)
{
    __shared__ __align__(16) char lds[16384];   // 2 x 8KB B-chunk buffers

    const int tid = threadIdx.x;
    const int w   = tid >> 6;
    const int l   = tid & 63;
    const int sub = l >> 4;
    const int lr  = l & 15;
    const int XF  = blockIdx.y;         // q (TERM0) / p (TERM1)

    const int scal = (TERM == 0) ? XF * 331776 : XF * 2654208;
    const int KSTR = (TERM == 0) ? 2654208 : 331776;   // x / y stride (elems)

    // per-lane per-mf base element offsets (incl. lane K-sub placement)
    int base[2][5];
    const int rowbase = blockIdx.x * 128 + w * 32;
    #pragma unroll
    for (int mf = 0; mf < 2; ++mf) {
        int row = rowbase + mf * 16 + lr;
        int a = row / 144;
        int b = row - a * 144;
        #pragma unroll
        for (int k = 0; k < 5; ++k) {
            int sh = ((TERM == 0) ? a : b) + k - 2;
            if (sh < 0) sh += 144;
            if (sh >= 144) sh -= 144;
            int off = (TERM == 0) ? (sh * 2304 + b * 16) : (a * 2304 + sh * 16);
            base[mf][k] = off + (sub >> 1) * KSTR + (sub & 1) * 8;
        }
    }

    const unsigned short* nb = nodalb + scal;
    const float* nfp = nodalf + scal;
    const char* Bb = (const char*)Bmat;

    f32x4 acc[2][8];
    #pragma unroll
    for (int mf = 0; mf < 2; ++mf)
        #pragma unroll
        for (int nf = 0; nf < 8; ++nf)
            acc[mf][nf] = (f32x4){0.f, 0.f, 0.f, 0.f};

    short8 Ab[3][2];        // bf16 path pipeline slots
    float4 Af[3][2][2];     // fp32 path pipeline slots

#define STAGE_B(buf_, ks_) do {                                              \
    gload_lds16(Bb + (ks_) * 8192 + tid * 16,                                \
                lds + (buf_) * 8192 + tid * 16);                             \
    gload_lds16(Bb + (ks_) * 8192 + 4096 + tid * 16,                         \
                lds + (buf_) * 8192 + 4096 + tid * 16);                      \
} while (0)

#define LOAD_A(slot_, ks_) do {                                              \
    const int k_  = (ks_) >> 2;                                              \
    const int xs_ = ((ks_) & 3) * 2 * KSTR;                                  \
    if (AB16) {                                                              \
        Ab[slot_][0] = *(const short8*)(nb + base[0][k_] + xs_);             \
        Ab[slot_][1] = *(const short8*)(nb + base[1][k_] + xs_);             \
    } else {                                                                 \
        const float* s0_ = nfp + base[0][k_] + xs_;                          \
        const float* s1_ = nfp + base[1][k_] + xs_;                          \
        Af[slot_][0][0] = *(const float4*)s0_;                               \
        Af[slot_][0][1] = *(const float4*)(s0_ + 4);                         \
        Af[slot_][1][0] = *(const float4*)s1_;                               \
        Af[slot_][1][1] = *(const float4*)(s1_ + 4);                         \
    } } while (0)

    // prologue
    STAGE_B(0, 0);
    LOAD_A(0, 0);
    LOAD_A(1, 1);
    __syncthreads();

    #pragma unroll
    for (int ks = 0; ks < 20; ++ks) {
        if (ks + 1 < 20) STAGE_B((ks + 1) & 1, ks + 1);
        if (ks + 2 < 20) LOAD_A((ks + 2) % 3, ks + 2);

        short8 a0, a1;
        if (AB16) {
            a0 = Ab[ks % 3][0];
            a1 = Ab[ks % 3][1];
        } else {
            #pragma unroll
            for (int e = 0; e < 4; ++e) {
                float v00 = ((const float*)&Af[ks % 3][0][0])[e];
                float v01 = ((const float*)&Af[ks % 3][0][1])[e];
                float v10 = ((const float*)&Af[ks % 3][1][0])[e];
                float v11 = ((const float*)&Af[ks % 3][1][1])[e];
                a0[e]     = (short)f2bf(v00);
                a0[e + 4] = (short)f2bf(v01);
                a1[e]     = (short)f2bf(v10);
                a1[e + 4] = (short)f2bf(v11);
            }
        }

        const char* bbase = lds + (ks & 1) * 8192 + sub * 2048 + lr * 16;
        #pragma unroll
        for (int nf = 0; nf < 8; ++nf) {
            short8 bf = *(const short8*)(bbase + nf * 256);
            acc[0][nf] = __builtin_amdgcn_mfma_f32_16x16x32_bf16(
                a0, bf, acc[0][nf], 0, 0, 0);
            acc[1][nf] = __builtin_amdgcn_mfma_f32_16x16x32_bf16(
                a1, bf, acc[1][nf], 0, 0, 0);
        }
        __syncthreads();
    }

    // ---- store: C frag layout col=lane&15, row=(lane>>4)*4+reg ----
    const int orow0 = blockIdx.x * 128 + w * 32 + sub * 4;
    #pragma unroll
    for (int mf = 0; mf < 2; ++mf) {
        #pragma unroll
        for (int nf = 0; nf < 8; ++nf) {
            int pq = (TERM == 0) ? (nf * 2654208 + XF * 331776)
                                 : (XF * 2654208 + nf * 331776);
            int b0 = pq + (orow0 + mf * 16) * 16 + lr;
            #pragma unroll
            for (int r = 0; r < 4; ++r) {
                float v = acc[mf][nf][r];
                if (TERM == 0) out[b0 + r * 16] = v;
                else           out[b0 + r * 16] += v;
            }
        }
    }
#undef STAGE_B
#undef LOAD_A
}

extern "C" void kernel_launch(void* const* d_in, const int* in_sizes, int n_in,
                              void* d_out, int out_size, void* d_ws, size_t ws_size,
                              hipStream_t stream) {
    const float* nodal = (const float*)d_in[0];
    const float* coef0 = (const float*)d_in[1];
    const float* coef1 = (const float*)d_in[2];
    const float* ws0   = (const float*)d_in[3];
    const float* ws1   = (const float*)d_in[4];
    const float* grid  = (const float*)d_in[5];
    float* outp = (float*)d_out;

    unsigned short* B      = (unsigned short*)d_ws;
    unsigned short* nodalb = (unsigned short*)((char*)d_ws + NB_OFF);
    const bool ab16 = ws_size >= (size_t)NB_OFF + (size_t)NODAL_ELEMS * 2;

    hipLaunchKernelGGL(build_b_kernel, dim3(640), dim3(256), 0, stream,
                       coef0, coef1, ws0, ws1, grid, B);
    if (ab16)
        hipLaunchKernelGGL(cvt_kernel, dim3(2048), dim3(256), 0, stream,
                           nodal, nodalb, NODAL_ELEMS / 4);

    dim3 g(162, 8);
    if (ab16) {
        hipLaunchKernelGGL((conv_mfma<0, true>), g, dim3(256), 0, stream,
                           nodal, nodalb, B, outp);
        hipLaunchKernelGGL((conv_mfma<1, true>), g, dim3(256), 0, stream,
                           nodal, nodalb, B + BSLAB, outp);
    } else {
        hipLaunchKernelGGL((conv_mfma<0, false>), g, dim3(256), 0, stream,
                           nodal, nodalb, B, outp);
        hipLaunchKernelGGL((conv_mfma<1, false>), g, dim3(256), 0, stream,
                           nodal, nodalb, B + BSLAB, outp);
    }
}

// Round 4
// 140.594 us; speedup vs baseline: 6.4790x; 1.0564x over previous
//
#include <hip/hip_runtime.h>

typedef __attribute__((ext_vector_type(8))) short short8;
typedef __attribute__((ext_vector_type(4))) float f32x4;

#define NODAL_ELEMS 21233664     // 8*8*144*144*16
#define BSLAB 81920              // 640*128 elements per direction
#define NB_OFF 327680            // byte offset of bf16 nodal in ws (2*BSLAB*2)

__device__ __forceinline__ unsigned short f2bf(float f) {
    unsigned int u = __float_as_uint(f);
    u += 0x7FFFu + ((u >> 16) & 1u);     // RNE
    return (unsigned short)(u >> 16);
}

__device__ __forceinline__ void gload_lds16(const void* g, void* l) {
    __builtin_amdgcn_global_load_lds(
        (const __attribute__((address_space(1))) unsigned int*)g,
        (__attribute__((address_space(3))) unsigned int*)l, 16, 0, 0);
}

// ---------------------------------------------------------------------------
// Build B matrices in fragment-order layout: B[d][kk=K/8][n=0..127][j=K%8]
// K = k*128 + x*16 + i ; n = X*16 + o ; value = ws[k,X,x]*fourier(coef,xy)[i,o]
// ---------------------------------------------------------------------------
__global__ void build_b_kernel(const float* __restrict__ coef0,
                               const float* __restrict__ coef1,
                               const float* __restrict__ ws0,
                               const float* __restrict__ ws1,
                               const float* __restrict__ grid,
                               unsigned short* __restrict__ B)
{
    const int bid = blockIdx.x;
    const int d   = (bid >= 320) ? 1 : 0;
    const int rem = bid - d * 320;
    const int k   = rem >> 6;
    const int X   = (rem >> 3) & 7;
    const int x   = rem & 7;

    const float* __restrict__ coef = d ? coef1 : coef0;
    const float* __restrict__ ws   = d ? ws1 : ws0;
    unsigned short* __restrict__ Bd = B + d * BSLAB;

    const float xy = (grid[X] - (grid[x] + (float)(k - 2))) * 0.25f;
    const int t = threadIdx.x;          // i*16 + o
    const int i = t >> 4;
    const int o = t & 15;

    float acc = 0.f;
    #pragma unroll 1
    for (int j = 0; j < 33; ++j) {
        float ang = 6.283185307179586f * (float)j * xy;
        float c = cosf(ang);
        float s = sinf(ang);
        float sc = (j == 0 || j == 32) ? 1.f : 2.f;
        float rr = coef[j * 256 + t];
        float ii = (j >= 1 && j <= 31) ? coef[(64 - j) * 256 + t] : 0.f;
        acc += sc * (c * rr - s * ii);
    }
    float val = acc * ws[(k * 8 + X) * 8 + x];

    const int kk = k * 16 + x * 2 + (i >> 3);
    const int jj = i & 7;
    const int n  = X * 16 + o;
    Bd[(kk * 128 + n) * 8 + jj] = f2bf(val);
}

// ---------------------------------------------------------------------------
// nodal fp32 -> bf16
// ---------------------------------------------------------------------------
__global__ void cvt_kernel(const float* __restrict__ in,
                           unsigned short* __restrict__ out, int n4)
{
    int idx = blockIdx.x * blockDim.x + threadIdx.x;
    int stride = gridDim.x * blockDim.x;
    for (int j = idx; j < n4; j += stride) {
        float4 v = ((const float4*)in)[j];
        ushort4 r;
        r.x = f2bf(v.x); r.y = f2bf(v.y); r.z = f2bf(v.z); r.w = f2bf(v.w);
        ((ushort4*)out)[j] = r;
    }
}

// ---------------------------------------------------------------------------
// MFMA conv kernel. TERM=0: fixed q, contract (k,x,i), N=(p,o), writes out.
//                  TERM=1: fixed p, contract (k,y,i), N=(q,o), accumulates.
// Block: 256 thr (4 waves). Tile: M=128 (wave M32xN128), N=128, K=640.
// K-loop chunked by outer k (5 chunks of 4 K-steps): B staged 32KB/chunk,
// double-buffered via global_load_lds; A register-prefetched 1 chunk ahead.
// ONE __syncthreads per chunk (drain amortized 4x vs per-K-step).
// grid: (162 M-tiles, 8 XF)
// ---------------------------------------------------------------------------
template<int TERM, bool AB16>
__global__ __launch_bounds__(256, 2)
void conv_mfma(const float* __restrict__ nodalf,
               const unsigned short* __restrict__ nodalb,
               const unsigned short* __restrict__ Bmat,
               float* __restrict__ out)
{
    __shared__ __align__(16) char lds[2][32768];   // 2 x 32KB B-chunk buffers

    const int tid = threadIdx.x;
    const int w   = tid >> 6;
    const int l   = tid & 63;
    const int sub = l >> 4;
    const int lr  = l & 15;
    const int XF  = blockIdx.y;         // q (TERM0) / p (TERM1)

    const int scal = (TERM == 0) ? XF * 331776 : XF * 2654208;
    const int KSTR = (TERM == 0) ? 2654208 : 331776;   // x / y stride (elems)

    // per-lane per-chunk(=k) base element offsets (incl. lane K-sub placement)
    int base[2][5];
    const int rowbase = blockIdx.x * 128 + w * 32;
    #pragma unroll
    for (int mf = 0; mf < 2; ++mf) {
        int row = rowbase + mf * 16 + lr;
        int a = row / 144;
        int b = row - a * 144;
        #pragma unroll
        for (int k = 0; k < 5; ++k) {
            int sh = ((TERM == 0) ? a : b) + k - 2;
            if (sh < 0) sh += 144;
            if (sh >= 144) sh -= 144;
            int off = (TERM == 0) ? (sh * 2304 + b * 16) : (a * 2304 + sh * 16);
            base[mf][k] = off + (sub >> 1) * KSTR + (sub & 1) * 8;
        }
    }

    const unsigned short* nb = nodalb + scal;
    const float* nfp = nodalf + scal;
    const char* Bb = (const char*)Bmat;

    f32x4 acc[2][8];
    #pragma unroll
    for (int mf = 0; mf < 2; ++mf)
        #pragma unroll
        for (int nf = 0; nf < 8; ++nf)
            acc[mf][nf] = (f32x4){0.f, 0.f, 0.f, 0.f};

    short8 Ab[2][4][2];        // [slot][ks'][mf] bf16 path
    float4 Af[2][4][2][2];     // fp32 fallback path

#define STAGE_B(buf_, c_) do {                                               \
    _Pragma("unroll")                                                        \
    for (int u_ = 0; u_ < 8; ++u_)                                           \
        gload_lds16(Bb + (c_) * 32768 + u_ * 4096 + tid * 16,                \
                    &lds[buf_][u_ * 4096 + tid * 16]);                       \
} while (0)

#define LOAD_A(slot_, c_) do {                                               \
    _Pragma("unroll")                                                        \
    for (int ksp_ = 0; ksp_ < 4; ++ksp_) {                                   \
        _Pragma("unroll")                                                    \
        for (int mf_ = 0; mf_ < 2; ++mf_) {                                  \
            if (AB16) {                                                      \
                Ab[slot_][ksp_][mf_] = *(const short8*)                      \
                    (nb + base[mf_][c_] + ksp_ * 2 * KSTR);                  \
            } else {                                                         \
                const float* s_ = nfp + base[mf_][c_] + ksp_ * 2 * KSTR;     \
                Af[slot_][ksp_][mf_][0] = *(const float4*)s_;                \
                Af[slot_][ksp_][mf_][1] = *(const float4*)(s_ + 4);          \
            }                                                                \
        }                                                                    \
    } } while (0)

    // prologue: stage + load chunk 0
    STAGE_B(0, 0);
    LOAD_A(0, 0);
    __syncthreads();

    #pragma unroll
    for (int c = 0; c < 5; ++c) {
        if (c < 4) {
            STAGE_B((c + 1) & 1, c + 1);
            LOAD_A((c + 1) & 1, c + 1);
        }

        #pragma unroll
        for (int ksp = 0; ksp < 4; ++ksp) {
            short8 a0, a1;
            if (AB16) {
                a0 = Ab[c & 1][ksp][0];
                a1 = Ab[c & 1][ksp][1];
            } else {
                #pragma unroll
                for (int e = 0; e < 4; ++e) {
                    a0[e]     = (short)f2bf(((const float*)&Af[c & 1][ksp][0][0])[e]);
                    a0[e + 4] = (short)f2bf(((const float*)&Af[c & 1][ksp][0][1])[e]);
                    a1[e]     = (short)f2bf(((const float*)&Af[c & 1][ksp][1][0])[e]);
                    a1[e + 4] = (short)f2bf(((const float*)&Af[c & 1][ksp][1][1])[e]);
                }
            }

            const char* bbase = lds[c & 1] + ksp * 8192 + sub * 2048 + lr * 16;
            #pragma unroll
            for (int nf = 0; nf < 8; ++nf) {
                short8 bf = *(const short8*)(bbase + nf * 256);
                acc[0][nf] = __builtin_amdgcn_mfma_f32_16x16x32_bf16(
                    a0, bf, acc[0][nf], 0, 0, 0);
                acc[1][nf] = __builtin_amdgcn_mfma_f32_16x16x32_bf16(
                    a1, bf, acc[1][nf], 0, 0, 0);
            }
        }

        if (c < 4) __syncthreads();
    }

    // ---- store: C frag layout col=lane&15, row=(lane>>4)*4+reg ----
    const int orow0 = blockIdx.x * 128 + w * 32 + sub * 4;
    #pragma unroll
    for (int mf = 0; mf < 2; ++mf) {
        #pragma unroll
        for (int nf = 0; nf < 8; ++nf) {
            int pq = (TERM == 0) ? (nf * 2654208 + XF * 331776)
                                 : (XF * 2654208 + nf * 331776);
            int b0 = pq + (orow0 + mf * 16) * 16 + lr;
            #pragma unroll
            for (int r = 0; r < 4; ++r) {
                float v = acc[mf][nf][r];
                if (TERM == 0) out[b0 + r * 16] = v;
                else           out[b0 + r * 16] += v;
            }
        }
    }
#undef STAGE_B
#undef LOAD_A
}

extern "C" void kernel_launch(void* const* d_in, const int* in_sizes, int n_in,
                              void* d_out, int out_size, void* d_ws, size_t ws_size,
                              hipStream_t stream) {
    const float* nodal = (const float*)d_in[0];
    const float* coef0 = (const float*)d_in[1];
    const float* coef1 = (const float*)d_in[2];
    const float* ws0   = (const float*)d_in[3];
    const float* ws1   = (const float*)d_in[4];
    const float* grid  = (const float*)d_in[5];
    float* outp = (float*)d_out;

    unsigned short* B      = (unsigned short*)d_ws;
    unsigned short* nodalb = (unsigned short*)((char*)d_ws + NB_OFF);
    const bool ab16 = ws_size >= (size_t)NB_OFF + (size_t)NODAL_ELEMS * 2;

    hipLaunchKernelGGL(build_b_kernel, dim3(640), dim3(256), 0, stream,
                       coef0, coef1, ws0, ws1, grid, B);
    if (ab16)
        hipLaunchKernelGGL(cvt_kernel, dim3(2048), dim3(256), 0, stream,
                           nodal, nodalb, NODAL_ELEMS / 4);

    dim3 g(162, 8);
    if (ab16) {
        hipLaunchKernelGGL((conv_mfma<0, true>), g, dim3(256), 0, stream,
                           nodal, nodalb, B, outp);
        hipLaunchKernelGGL((conv_mfma<1, true>), g, dim3(256), 0, stream,
                           nodal, nodalb, B + BSLAB, outp);
    } else {
        hipLaunchKernelGGL((conv_mfma<0, false>), g, dim3(256), 0, stream,
                           nodal, nodalb, B, outp);
        hipLaunchKernelGGL((conv_mfma<1, false>), g, dim3(256), 0, stream,
                           nodal, nodalb, B + BSLAB, outp);
    }
}